// Round 7
// baseline (466.002 us; speedup 1.0000x reference)
//
#include <hip/hip_runtime.h>
#include <hip/hip_cooperative_groups.h>
#include <hip/hip_bf16.h>

namespace cg = cooperative_groups;

#define NN 256
#define FD 128
#define HH 256
#define G3 384
#define STEPS 6
#define NB 256           // grid blocks == CU count (cooperative co-residency)
#define TPB 512
#define PO 896           // proj cols: Ai[0:256) | Aj[256:512) | gh[512:896)

typedef __hip_bfloat16 bf16;

// ---- device globals (zero-init at load; NOT harness-poisoned) ----
__device__ float g_aj[2][1024*HH];      // double-buffered Aj rows [node][h]
__device__ float g_PT[FD*PO];           // [f][col]
__device__ float g_pbias[PO];
__device__ float g_w1e[HH];
__device__ float g_W2f[HH*HH];          // f32 copy of W2
__device__ float g_WihT[HH*G3];         // [h2][g]
__device__ float g_MT[HH*G3];           // [k][g] = (Wih@W2)[g][k]
__device__ float g_b2f[HH];
__device__ float g_bv[G3];
__device__ float g_bihf[G3];

__device__ __forceinline__ float b2f(bf16 v){ return __bfloat162float(v); }
__device__ __forceinline__ float ldin(const void* p, int i, int isb){
  return isb ? b2f(((const bf16*)p)[i]) : ((const float*)p)[i];
}
__device__ __forceinline__ int probe_bf16(const void* mask){
  return ((const unsigned short*)mask)[0] == 0x3F80 ? 1 : 0;
}

__global__ __launch_bounds__(TPB, 2) void k_all(
    const void* __restrict__ x,   const void* __restrict__ adj,
    const void* __restrict__ mask,const void* __restrict__ W1,
    const void* __restrict__ b1,  const void* __restrict__ W2,
    const void* __restrict__ b2,  const void* __restrict__ Wih,
    const void* __restrict__ bih, const void* __restrict__ Whh,
    const void* __restrict__ bhh, void* __restrict__ out){
  cg::grid_group grid = cg::this_grid();

  __shared__ __align__(16) float tmp[16*G3];     // 24 KB: S-red / U-part / P-partial
  __shared__ __align__(16) float avsh[NN*8];     // 8 KB [j][r][2]
  __shared__ __align__(16) float hsh[4][FD];     // 2 KB
  __shared__ __align__(16) float Ai[4][HH];      // 4 KB
  __shared__ __align__(16) float ghs[4][G3];     // 6 KB
  __shared__ __align__(16) float Ssh[4][HH];     // 4 KB
  __shared__ float redd[8], dsh[4], msh[4];

  const int blk = blockIdx.x, tid = threadIdx.x;
  const int n0 = blk*4, b = blk >> 6;
  const int isb = probe_bf16(mask);

  // ================= I1: inputs -> LDS/global f32 layouts =================
  {
    int r = tid >> 7, hp = tid & 127;
    int node = n0 + r;
    float mi = ldin(mask, node, isb);
    float mj0 = ldin(mask, b*NN + 2*hp,   isb);
    float mj1 = ldin(mask, b*NN + 2*hp+1, isb);
    float a0 = ldin(adj, node*NN + 2*hp,   isb);
    float a1 = ldin(adj, node*NN + 2*hp+1, isb);
    float v0 = (a0 > 0.f && mj0 > 0.f && mi > 0.f) ? 1.f : 0.f;
    float v1 = (a1 > 0.f && mj1 > 0.f && mi > 0.f) ? 1.f : 0.f;
    avsh[(2*hp)*8   + r*2]     = a0;
    avsh[(2*hp)*8   + r*2 + 1] = v0;
    avsh[(2*hp+1)*8 + r*2]     = a1;
    avsh[(2*hp+1)*8 + r*2 + 1] = v1;
    float s = v0 + v1;
    #pragma unroll
    for (int o = 32; o > 0; o >>= 1) s += __shfl_down(s, o, 64);
    if ((tid & 63) == 0) redd[tid >> 6] = s;
    if (hp == 0) msh[r] = mi;
    hsh[r][hp] = ldin(x, node*FD + hp, isb);
  }
  if (tid < 448){                       // PT slice
    int i = blk*448 + tid;
    int f = i / PO, o = i % PO;
    float v;
    if (o < 256)      v = ldin(W1, o*257 + f, isb);
    else if (o < 512) v = ldin(W1, (o-256)*257 + FD + f, isb);
    else              v = ldin(Whh, (o-512)*FD + f, isb);
    g_PT[i] = v;
  }
  if (tid < 384) g_WihT[blk*384 + tid] = ldin(Wih, tid*HH + blk, isb);
  if (tid < 256) g_W2f[blk*256 + tid] = ldin(W2, blk*256 + tid, isb);
  if (blk == 0 && tid < 256) g_b2f[tid] = ldin(b2, tid, isb);
  if (blk == 1 && tid < 384) g_bihf[tid] = ldin(bih, tid, isb);
  if (blk == 2 && tid < 256) g_w1e[tid] = ldin(W1, tid*257 + 256, isb);
  if (blk == 3){
    for (int i = tid; i < PO; i += TPB)      // grid-stride: TPB=512 < PO=896!
      g_pbias[i] = (i < 256) ? ldin(b1, i, isb)
                 : (i < 512) ? 0.f : ldin(bhh, i - 512, isb);
  }
  __syncthreads();
  if (tid < 4) dsh[tid] = redd[2*tid] + redd[2*tid + 1];
  grid.sync();

  // ================= I2: MT[k=blk][g] (+ bv on blk 0) =================
  if (tid < 384){
    int g = tid;
    const float* w2c = g_W2f + blk;     // column k=blk, stride 256
    float acc = 0.f;
    #pragma unroll 8
    for (int h2 = 0; h2 < HH; ++h2)
      acc = fmaf(w2c[h2*HH], g_WihT[h2*G3 + g], acc);
    g_MT[blk*G3 + g] = acc;
    if (blk == 0){
      float accb = 0.f;
      #pragma unroll 8
      for (int h2 = 0; h2 < HH; ++h2)
        accb = fmaf(g_b2f[h2], g_WihT[h2*G3 + g], accb);
      g_bv[g] = accb;
    }
  }

  // ================= P0: initial proj (writes Ai, ghs, g_aj[0]) =================
  {
    int c = tid & 255, fh = tid >> 8;
    float4 acc[4];
    #pragma unroll
    for (int r = 0; r < 4; ++r) acc[r] = make_float4(0.f,0.f,0.f,0.f);
    if (c < 224){
      const float4* PT4 = (const float4*)g_PT + fh*64*224 + c;
      #pragma unroll 4
      for (int f = 0; f < 64; ++f){
        float4 w = *PT4; PT4 += 224;
        #pragma unroll
        for (int r = 0; r < 4; ++r){
          float hv = hsh[r][fh*64 + f];
          acc[r].x = fmaf(hv, w.x, acc[r].x);
          acc[r].y = fmaf(hv, w.y, acc[r].y);
          acc[r].z = fmaf(hv, w.z, acc[r].z);
          acc[r].w = fmaf(hv, w.w, acc[r].w);
        }
      }
      if (fh == 1){
        #pragma unroll
        for (int r = 0; r < 4; ++r) ((float4*)tmp)[r*224 + c] = acc[r];
      }
    }
    __syncthreads();
    if (fh == 0 && c < 224){
      float4 pb = ((const float4*)g_pbias)[c];
      #pragma unroll
      for (int r = 0; r < 4; ++r){
        float4 p = ((float4*)tmp)[r*224 + c];
        float4 res = make_float4(acc[r].x + p.x + pb.x, acc[r].y + p.y + pb.y,
                                 acc[r].z + p.z + pb.z, acc[r].w + p.w + pb.w);
        if (c < 64)        ((float4*)Ai[r])[c] = res;
        else if (c < 128)  ((float4*)(g_aj[0] + (n0+r)*HH))[c - 64] = res;
        else               ((float4*)ghs[r])[c - 128] = res;
      }
    }
  }
  grid.sync();

  // hoisted step-invariant registers
  const int hp_ = tid & 127, q_ = tid >> 7;
  float2 w12 = ((const float2*)g_w1e)[hp_];
  float bvg = 0.f, bihg = 0.f;
  if (tid < 384){ bvg = g_bv[tid]; bihg = g_bihf[tid]; }

  // ================= steps =================
  for (int s = 0; s < STEPS; ++s){
    // ---- S: Ssh[r][h] = sum_j relu(Ai + Aj + adj*w1e)*valid ----
    {
      float2 Ai2[4], acc[4];
      #pragma unroll
      for (int r = 0; r < 4; ++r){
        Ai2[r] = ((const float2*)Ai[r])[hp_];
        acc[r] = make_float2(0.f, 0.f);
      }
      const float* ajp = g_aj[s & 1] + (b*NN + q_*64)*HH + 2*hp_;
      const float4* avp = ((const float4*)avsh) + q_*128;
      #pragma unroll 2
      for (int j = 0; j < 64; ++j){
        float2 a2 = *(const float2*)ajp; ajp += HH;
        float4 av01 = avp[2*j];
        float4 av23 = avp[2*j + 1];
        float adv[4] = {av01.x, av01.z, av23.x, av23.z};
        float vmv[4] = {av01.y, av01.w, av23.y, av23.w};
        #pragma unroll
        for (int r = 0; r < 4; ++r){
          float vx = Ai2[r].x + a2.x;
          float vy = Ai2[r].y + a2.y;
          vx = fmaf(adv[r], w12.x, vx);
          vy = fmaf(adv[r], w12.y, vy);
          vx = fmaxf(vx, 0.f); vy = fmaxf(vy, 0.f);
          acc[r].x = fmaf(vx, vmv[r], acc[r].x);
          acc[r].y = fmaf(vy, vmv[r], acc[r].y);
        }
      }
      if (q_){
        #pragma unroll
        for (int r = 0; r < 4; ++r)
          ((float2*)tmp)[((q_-1)*4 + r)*128 + hp_] = acc[r];
      }
      __syncthreads();
      if (q_ == 0){
        #pragma unroll
        for (int r = 0; r < 4; ++r){
          float2 sv = acc[r];
          float2 p0 = ((float2*)tmp)[(0*4 + r)*128 + hp_];
          float2 p1 = ((float2*)tmp)[(1*4 + r)*128 + hp_];
          float2 p2 = ((float2*)tmp)[(2*4 + r)*128 + hp_];
          sv.x += p0.x + p1.x + p2.x;
          sv.y += p0.y + p1.y + p2.y;
          ((float2*)Ssh[r])[hp_] = sv;
        }
      }
    }
    __syncthreads();

    // ---- U: gi = S@M + deg*bv + bih ; GRU ----
    if (tid < 384){
      int c = tid % 96, sub = tid / 96, k0 = sub*64;
      float4 acc[4];
      #pragma unroll
      for (int r = 0; r < 4; ++r) acc[r] = make_float4(0.f,0.f,0.f,0.f);
      const float4* MT4 = (const float4*)g_MT;
      #pragma unroll 2
      for (int k = 0; k < 64; ++k){
        float4 m = MT4[(k0 + k)*96 + c];
        #pragma unroll
        for (int r = 0; r < 4; ++r){
          float sv = Ssh[r][k0 + k];
          acc[r].x = fmaf(sv, m.x, acc[r].x);
          acc[r].y = fmaf(sv, m.y, acc[r].y);
          acc[r].z = fmaf(sv, m.z, acc[r].z);
          acc[r].w = fmaf(sv, m.w, acc[r].w);
        }
      }
      #pragma unroll
      for (int r = 0; r < 4; ++r)
        ((float4*)(tmp + (sub*4 + r)*G3))[c] = acc[r];
    }
    __syncthreads();
    if (tid < 384){
      int g = tid;
      #pragma unroll
      for (int r = 0; r < 4; ++r){
        float gi = tmp[(0 + r)*G3 + g] + tmp[(4 + r)*G3 + g]
                 + tmp[(8 + r)*G3 + g] + tmp[(12 + r)*G3 + g]
                 + dsh[r]*bvg + bihg;
        float gh = ghs[r][g];
        tmp[r*G3 + g] = (g < 256) ? (gi + gh) : gi;   // A
      }
    }
    __syncthreads();
    if (tid < 128){
      int f = tid;
      #pragma unroll
      for (int r = 0; r < 4; ++r){
        float rr = 1.f/(1.f + __expf(-tmp[r*G3 + f]));
        float zz = 1.f/(1.f + __expf(-tmp[r*G3 + 128 + f]));
        float hn = ghs[r][256 + f];
        float narg = tmp[r*G3 + 256 + f] + rr*hn;
        float e = __expf(2.f*narg);
        float nn = 1.f - 2.f/(e + 1.f);
        float hv = (1.f - zz)*nn + zz*hsh[r][f];
        hv *= msh[r];
        hsh[r][f] = hv;
        if (s == STEPS-1){
          int node = n0 + r;
          if (isb) ((bf16*)out)[node*FD + f] = __float2bfloat16(hv);
          else     ((float*)out)[node*FD + f] = hv;
        }
      }
    }
    __syncthreads();

    // ---- P: proj of new h (skip after last step) ----
    if (s < STEPS-1){
      int c = tid & 255, fh = tid >> 8;
      float4 acc[4];
      #pragma unroll
      for (int r = 0; r < 4; ++r) acc[r] = make_float4(0.f,0.f,0.f,0.f);
      if (c < 224){
        const float4* PT4 = (const float4*)g_PT + fh*64*224 + c;
        #pragma unroll 4
        for (int f = 0; f < 64; ++f){
          float4 w = *PT4; PT4 += 224;
          #pragma unroll
          for (int r = 0; r < 4; ++r){
            float hv = hsh[r][fh*64 + f];
            acc[r].x = fmaf(hv, w.x, acc[r].x);
            acc[r].y = fmaf(hv, w.y, acc[r].y);
            acc[r].z = fmaf(hv, w.z, acc[r].z);
            acc[r].w = fmaf(hv, w.w, acc[r].w);
          }
        }
        if (fh == 1){
          #pragma unroll
          for (int r = 0; r < 4; ++r) ((float4*)tmp)[r*224 + c] = acc[r];
        }
      }
      __syncthreads();
      if (fh == 0 && c < 224){
        float4 pb = ((const float4*)g_pbias)[c];
        int wbuf = (s + 1) & 1;
        #pragma unroll
        for (int r = 0; r < 4; ++r){
          float4 p = ((float4*)tmp)[r*224 + c];
          float4 res = make_float4(acc[r].x + p.x + pb.x, acc[r].y + p.y + pb.y,
                                   acc[r].z + p.z + pb.z, acc[r].w + p.w + pb.w);
          if (c < 64)        ((float4*)Ai[r])[c] = res;
          else if (c < 128)  ((float4*)(g_aj[wbuf] + (n0+r)*HH))[c - 64] = res;
          else               ((float4*)ghs[r])[c - 128] = res;
        }
      }
      grid.sync();
    }
  }
}

extern "C" void kernel_launch(void* const* d_in, const int* in_sizes, int n_in,
                              void* d_out, int out_size, void* d_ws, size_t ws_size,
                              hipStream_t stream){
  (void)in_sizes; (void)n_in; (void)out_size; (void)d_ws; (void)ws_size;
  const void* x    = d_in[0];
  const void* adj  = d_in[1];
  const void* mask = d_in[2];
  const void* W1   = d_in[3];
  const void* b1   = d_in[4];
  const void* W2   = d_in[5];
  const void* b2   = d_in[6];
  const void* Wih  = d_in[7];
  const void* bih  = d_in[8];
  const void* Whh  = d_in[9];
  const void* bhh  = d_in[10];
  void* out = d_out;

  void* args[12] = { &x, &adj, &mask, &W1, &b1, &W2, &b2, &Wih, &bih, &Whh,
                     &bhh, &out };
  hipLaunchCooperativeKernel((const void*)k_all, dim3(NB), dim3(TPB), args, 0,
                             stream);
}